// Round 4
// baseline (909.890 us; speedup 1.0000x reference)
//
#include <hip/hip_runtime.h>
#include <hip/hip_bf16.h>

#define B_   4
#define M_   8192
#define N_   32768
#define EPS_ 1e-5f
#define TBL  1048576   // 4 * 64^3 dense hash table
#define GUARD 8192     // negative-offset guard for window probes

typedef short short8 __attribute__((ext_vector_type(8)));   // 8 bf16 (4 VGPRs)
typedef float f32x4  __attribute__((ext_vector_type(4)));   // 4 fp32 acc

// ---------------------------------------------------------------- prep
__global__ __launch_bounds__(256) void prep_kernel(const int* __restrict__ coords,
                                                   int* __restrict__ table,
                                                   int* __restrict__ packed,
                                                   int* __restrict__ keyb) {
    int n = blockIdx.x * 256 + threadIdx.x;
    int b = coords[4*n+0], x = coords[4*n+1], y = coords[4*n+2], z = coords[4*n+3];
    packed[n] = (x << 10) | (y << 5) | z;
    int key = ((b*64 + x+1)*64 + y+1)*64 + (z+1);
    keyb[n] = key;
    table[key] = n;
}

// ---------------------------------------------------------------- w3 -> bf16 MFMA B-fragment layout
// w3f[t*8+j], t = (o<<11)|(ks<<9)|(ct<<6)|lane :
//   value = bf16(w3[o][c][n]), c = ks*32 + (lane>>4)*8 + j, n = ct*16 + (lane&15)
__global__ __launch_bounds__(256) void w3pack_kernel(const float* __restrict__ w3,
                                                     ushort* __restrict__ w3f) {
    int t = blockIdx.x * 256 + threadIdx.x;   // 27*2048 = 55296 threads exactly
    int lane = t & 63;
    int ct   = (t >> 6) & 7;
    int ks   = (t >> 9) & 3;
    int o    = t >> 11;
    int quad = lane >> 4, l15 = lane & 15;
    int n = ct*16 + l15;
    const float* src = w3 + o*16384;
    ushort out8[8];
#pragma unroll
    for (int j = 0; j < 8; ++j) {
        int c = ks*32 + quad*8 + j;
        float v = src[c*128 + n];
        __hip_bfloat16 bv = __float2bfloat16(v);
        ushort u; __builtin_memcpy(&u, &bv, 2);
        out8[j] = u;
    }
    *(uint4*)&w3f[t*8] = *(uint4*)out8;
}

// ---------------------------------------------------------------- kNN via radius-2 window
__global__ __launch_bounds__(256) void knn_window_kernel(const int* __restrict__ table,
                                                         const int* __restrict__ keyb,
                                                         int* __restrict__ nbr,
                                                         int* __restrict__ flagcnt,
                                                         int* __restrict__ flaglist) {
    __shared__ int okey_sh[125], d2_sh[125];
    __shared__ int tops[256 * 8];
    int tid = threadIdx.x;
    if (tid < 125) {
        int dx = tid / 25 - 2, rr = tid % 25, dy = rr / 5 - 2, dz = rr % 5 - 2;
        okey_sh[tid] = dx * 4096 + dy * 64 + dz;
        d2_sh[tid]   = dx*dx + dy*dy + dz*dz;
    }
    __syncthreads();

    int q   = blockIdx.x * 64 + (tid >> 2);
    int sub = tid & 3;
    int kb  = keyb[q];

    int top[8];
#pragma unroll
    for (int k = 0; k < 8; ++k) top[k] = 0x7FFFFFFF;

    int base = sub * 32;
    int cnt  = (sub == 3) ? 29 : 32;
    for (int i = 0; i < cnt; ++i) {
        int idx = base + i;
        int j = table[kb + okey_sh[idx]];
        if (j >= 0) {
            int key = (d2_sh[idx] << 13) | (j & 8191);
            if (key < top[7]) {
#pragma unroll
                for (int k = 7; k >= 1; --k)
                    top[k] = (key < top[k]) ? max(key, top[k-1]) : top[k];
                top[0] = min(key, top[0]);
            }
        }
    }
#pragma unroll
    for (int k = 0; k < 8; ++k) tops[tid*8 + k] = top[k];
    __syncthreads();

    if (sub == 0) {
        const int* L = &tops[tid*8];
        int ia0 = 0, ia1 = 0, ia2 = 0, ia3 = 0;
        int res[8];
#pragma unroll
        for (int k = 0; k < 8; ++k) {
            int v0 = L[ia0], v1 = L[8 + ia1], v2 = L[16 + ia2], v3 = L[24 + ia3];
            int m01 = min(v0, v1), m23 = min(v2, v3);
            int m = min(m01, m23);
            res[k] = m;
            if (m == v0) ++ia0; else if (m == v1) ++ia1;
            else if (m == v2) ++ia2; else ++ia3;
        }
        int bb = q & ~(M_-1);
        if ((res[7] >> 13) <= 8) {
#pragma unroll
            for (int k = 0; k < 8; ++k) nbr[q*8 + k] = bb + (res[k] & 8191);
        } else {
            int pos = atomicAdd(flagcnt, 1);
            flaglist[pos] = q;
        }
    }
}

// ---------------------------------------------------------------- brute-force cleanup
__global__ __launch_bounds__(256) void knn_bf_kernel(const int* __restrict__ packed,
                                                     const int* __restrict__ flagcnt,
                                                     const int* __restrict__ flaglist,
                                                     int* __restrict__ nbr) {
    __shared__ int tops[256 * 8];
    int tid = threadIdx.x;
    int cnt = *flagcnt;
    for (int f = blockIdx.x; f < cnt; f += gridDim.x) {
        int n = flaglist[f];
        int bb = n & ~(M_-1);
        int p = packed[n];
        int qx = (p >> 10) & 31, qy = (p >> 5) & 31, qz = p & 31;
        int top[8];
#pragma unroll
        for (int k = 0; k < 8; ++k) top[k] = 0x7FFFFFFF;
        for (int j = tid; j < M_; j += 256) {
            int c = packed[bb + j];
            int dx = qx - ((c >> 10) & 31);
            int dy = qy - ((c >> 5) & 31);
            int dz = qz - (c & 31);
            int d2 = dx*dx + dy*dy + dz*dz;
            int key = (d2 << 13) | j;
            if (key < top[7]) {
#pragma unroll
                for (int k = 7; k >= 1; --k)
                    top[k] = (key < top[k]) ? max(key, top[k-1]) : top[k];
                top[0] = min(key, top[0]);
            }
        }
#pragma unroll
        for (int k = 0; k < 8; ++k) tops[tid*8 + k] = top[k];
        __syncthreads();
        for (int stride = 128; stride >= 1; stride >>= 1) {
            if (tid < stride) {
                int* A  = &tops[tid*8];
                int* Bp = &tops[(tid+stride)*8];
                int r[8]; int ia = 0, ib = 0;
#pragma unroll
                for (int k = 0; k < 8; ++k) {
                    int a = A[ia], b2 = Bp[ib];
                    if (a <= b2) { r[k] = a; ++ia; } else { r[k] = b2; ++ib; }
                }
#pragma unroll
                for (int k = 0; k < 8; ++k) A[k] = r[k];
            }
            __syncthreads();
        }
        if (tid == 0) {
#pragma unroll
            for (int k = 0; k < 8; ++k) nbr[n*8 + k] = bb + (tops[k] & 8191);
        }
        __syncthreads();
    }
}

// ---------------------------------------------------------------- 1x1 conv + BN1 partials
__global__ __launch_bounds__(256) void h1_kernel(const float* __restrict__ feats,
                                                 const int* __restrict__ nbr,
                                                 const float* __restrict__ w1,
                                                 float* __restrict__ hpre,
                                                 float* __restrict__ part1) {
    __shared__ float comb[16][72];
    __shared__ float red[256];
    int tid = threadIdx.x;
    int rowbase = blockIdx.x * 16;
    if (tid < 144) {
        int r = tid / 9, s = tid % 9;
        int grow = rowbase + r;
        int idx = (s == 0) ? grow : nbr[grow*8 + (s-1)];
        const float4* f = (const float4*)(feats + idx * 8);
        float4 a = f[0], b = f[1];
        float* dp = &comb[r][s*8];
        dp[0]=a.x; dp[1]=a.y; dp[2]=a.z; dp[3]=a.w;
        dp[4]=b.x; dp[5]=b.y; dp[6]=b.z; dp[7]=b.w;
    }
    __syncthreads();
    int c = tid & 127, rh = tid >> 7;
    float acc[8];
#pragma unroll
    for (int i = 0; i < 8; ++i) acc[i] = 0.f;
    for (int s = 0; s < 72; ++s) {
        float w = w1[s*128 + c];
#pragma unroll
        for (int i = 0; i < 8; ++i)
            acc[i] += comb[rh*8 + i][s] * w;
    }
    float s1 = 0.f, q1 = 0.f;
#pragma unroll
    for (int i = 0; i < 8; ++i) {
        hpre[(rowbase + rh*8 + i)*128 + c] = acc[i];
        s1 += acc[i]; q1 += acc[i]*acc[i];
    }
    red[tid] = s1;
    __syncthreads();
    if (tid < 128) part1[blockIdx.x*256 + tid] = red[tid] + red[tid+128];
    __syncthreads();
    red[tid] = q1;
    __syncthreads();
    if (tid < 128) part1[blockIdx.x*256 + 128 + tid] = red[tid] + red[tid+128];
}

// ---------------------------------------------------------------- BN stats (parametric over #partial blocks)
__global__ __launch_bounds__(128) void stats_kernel(const float* __restrict__ part, int nb,
                                                    const float* __restrict__ g,
                                                    const float* __restrict__ bias,
                                                    float* __restrict__ scale,
                                                    float* __restrict__ shift) {
    int c = threadIdx.x;
    float s = 0.f, q = 0.f;
    for (int b = 0; b < nb; ++b) {
        s += part[b*256 + c];
        q += part[b*256 + 128 + c];
    }
    float mu  = s / (float)N_;
    float var = q / (float)N_ - mu*mu;
    float inv = rsqrtf(var + EPS_);
    float sc  = inv * g[c];
    scale[c] = sc;
    shift[c] = bias[c] - mu * sc;
}

// BN+ReLU -> bf16 (conv3 A operand)
__global__ __launch_bounds__(256) void bnrelu_bf16_kernel(const float* __restrict__ x,
                                                          const float* __restrict__ scale,
                                                          const float* __restrict__ shift,
                                                          ushort* __restrict__ y) {
    int i = blockIdx.x * 256 + threadIdx.x;
    float4 v = ((const float4*)x)[i];
    int c = (i * 4) & 127;
    v.x = fmaxf(0.f, v.x*scale[c]   + shift[c]);
    v.y = fmaxf(0.f, v.y*scale[c+1] + shift[c+1]);
    v.z = fmaxf(0.f, v.z*scale[c+2] + shift[c+2]);
    v.w = fmaxf(0.f, v.w*scale[c+3] + shift[c+3]);
    ushort o[4];
#pragma unroll
    for (int k = 0; k < 4; ++k) {
        float f = (&v.x)[k];
        __hip_bfloat16 bv = __float2bfloat16(f);
        __builtin_memcpy(&o[k], &bv, 2);
    }
    ((ushort4*)y)[i] = make_ushort4(o[0], o[1], o[2], o[3]);
}

// ---------------------------------------------------------------- 3^3 sparse conv: dbuf bf16 MFMA gather-GEMM
// 128 rows x 128 cols per block, grid 256 (1 block/CU). 4 waves, each 64x64 = 4x4 tiles
// of 16x16x32. Double-buffered LDS (A, B, jsh) -> ONE barrier per offset; next offset's
// global loads live in VGPRs across the MFMA section (overlap). Epilogue: BN2 partials.
#define ASTR 136    // 128 + 8 ushorts pad: 2-way banks only (free), 16B aligned
__global__ __launch_bounds__(256, 1) void conv3_mfma_kernel(const ushort* __restrict__ hb,
                                                            const ushort* __restrict__ w3f,
                                                            const int* __restrict__ table,
                                                            const int* __restrict__ keyb,
                                                            float* __restrict__ h2,
                                                            float* __restrict__ part2) {
    __shared__ ushort As[2][128 * ASTR];   // 2 x 34816 B
    __shared__ ushort Bs[2][16384];        // 2 x 32768 B
    __shared__ int jsh[2][128];
    int tid = threadIdx.x;
    int lane = tid & 63, wid = tid >> 6;
    int quad = lane >> 4, l15 = lane & 15;
    int rg = wid >> 1, cg = wid & 1;       // row-group / col-group (64 each)
    int rowbase = blockIdx.x * 128;

    f32x4 acc[4][4];
#pragma unroll
    for (int rt = 0; rt < 4; ++rt)
#pragma unroll
        for (int ct = 0; ct < 4; ++ct)
            acc[rt][ct] = (f32x4){0.f, 0.f, 0.f, 0.f};

    const int gr = tid >> 4, gc16 = tid & 15;   // this thread's gather rows: gr + 16*i

    // okey(o)
#define OKEY(o) (((o)/9 - 1)*4096 + (((o)/3)%3 - 1)*64 + ((o)%3 - 1))

    // prologue: jsh(0), jsh(1)
    if (tid < 128) jsh[0][tid] = table[keyb[rowbase + tid] + OKEY(0)];
    else           jsh[1][tid-128] = table[keyb[rowbase + tid-128] + OKEY(1)];
    __syncthreads();
    // stage offset 0 into buffer 0
    {
        uint4 a[8], b[8];
#pragma unroll
        for (int i = 0; i < 8; ++i) {
            int r = gr + 16*i;
            int j = jsh[0][r];
            a[i] = (j >= 0) ? *(const uint4*)&hb[j*128 + gc16*8] : make_uint4(0,0,0,0);
            b[i] = *(const uint4*)&w3f[(i*256 + tid)*8];
        }
#pragma unroll
        for (int i = 0; i < 8; ++i) {
            int r = gr + 16*i;
            *(uint4*)&As[0][r*ASTR + gc16*8] = a[i];
            *(uint4*)&Bs[0][(i*256 + tid)*8] = b[i];
        }
    }
    __syncthreads();

    for (int o = 0; o < 27; ++o) {
        int p = o & 1;
        uint4 pa[8], pb[8];
        int pj = 0;
        bool pre  = (o + 1 < 27);
        bool pre2 = (o + 2 < 27);
        if (pre) {
            const ushort* wsrc = w3f + (o+1)*16384;
#pragma unroll
            for (int i = 0; i < 8; ++i) {
                int r = gr + 16*i;
                int j = jsh[p^1][r];
                pa[i] = (j >= 0) ? *(const uint4*)&hb[j*128 + gc16*8] : make_uint4(0,0,0,0);
                pb[i] = *(const uint4*)&wsrc[(i*256 + tid)*8];
            }
        }
        if (pre2 && tid < 128) pj = table[keyb[rowbase + tid] + OKEY(o+2)];

        // compute: 4 K-steps x 16 MFMAs from buffer p
#pragma unroll
        for (int ks = 0; ks < 4; ++ks) {
            short8 af[4], bfr[4];
#pragma unroll
            for (int rt = 0; rt < 4; ++rt)
                af[rt] = *(const short8*)&As[p][(rg*64 + rt*16 + l15)*ASTR + ks*32 + quad*8];
#pragma unroll
            for (int ct = 0; ct < 4; ++ct)
                bfr[ct] = *(const short8*)&Bs[p][((ks*8 + cg*4 + ct)*64 + lane)*8];
#pragma unroll
            for (int rt = 0; rt < 4; ++rt)
#pragma unroll
                for (int ct = 0; ct < 4; ++ct)
                    acc[rt][ct] = __builtin_amdgcn_mfma_f32_16x16x32_bf16(af[rt], bfr[ct], acc[rt][ct], 0, 0, 0);
        }

        if (pre) {
#pragma unroll
            for (int i = 0; i < 8; ++i) {
                int r = gr + 16*i;
                *(uint4*)&As[p^1][r*ASTR + gc16*8] = pa[i];
                *(uint4*)&Bs[p^1][(i*256 + tid)*8] = pb[i];
            }
        }
        if (pre2 && tid < 128) jsh[p][tid] = pj;
        __syncthreads();
    }

    // epilogue: store h2 + BN2 partials (sum/sumsq per column)
    float s[4] = {0,0,0,0}, q[4] = {0,0,0,0};
#pragma unroll
    for (int rt = 0; rt < 4; ++rt)
#pragma unroll
        for (int ct = 0; ct < 4; ++ct)
#pragma unroll
            for (int r = 0; r < 4; ++r) {
                float v = acc[rt][ct][r];
                int row = rowbase + rg*64 + rt*16 + quad*4 + r;
                int col = cg*64 + ct*16 + l15;
                h2[row*128 + col] = v;
                s[ct] += v; q[ct] += v*v;
            }
#pragma unroll
    for (int ct = 0; ct < 4; ++ct) {
        s[ct] += __shfl_xor(s[ct], 16); s[ct] += __shfl_xor(s[ct], 32);
        q[ct] += __shfl_xor(q[ct], 16); q[ct] += __shfl_xor(q[ct], 32);
    }
    if (quad == 0) {
        int base = (blockIdx.x*2 + rg)*256;
#pragma unroll
        for (int ct = 0; ct < 4; ++ct) {
            part2[base + cg*64 + ct*16 + l15]       = s[ct];
            part2[base + 128 + cg*64 + ct*16 + l15] = q[ct];
        }
    }
}

// ---------------------------------------------------------------- fused BN2+ReLU+final 1x1 conv
__global__ __launch_bounds__(256) void out_kernel(const float* __restrict__ h2,
                                                  const float* __restrict__ wout,
                                                  const float* __restrict__ scale,
                                                  const float* __restrict__ shift,
                                                  float* __restrict__ out) {
    int tid = threadIdx.x;
    int r = tid >> 4, d = tid & 15;
    int row = blockIdx.x * 16 + r;
    float acc = 0.f;
    for (int c = 0; c < 128; ++c) {
        float v = fmaxf(0.f, h2[row*128 + c]*scale[c] + shift[c]);
        acc += v * wout[c*16 + d];
    }
    out[row*16 + d] = acc;
}

// ---------------------------------------------------------------- launch
extern "C" void kernel_launch(void* const* d_in, const int* in_sizes, int n_in,
                              void* d_out, int out_size, void* d_ws, size_t ws_size,
                              hipStream_t stream) {
    const int*   coords = (const int*)d_in[0];
    const float* feats  = (const float*)d_in[1];
    const float* w1     = (const float*)d_in[2];
    const float* g1     = (const float*)d_in[3];
    const float* b1     = (const float*)d_in[4];
    const float* w3     = (const float*)d_in[5];
    const float* g2     = (const float*)d_in[6];
    const float* b2     = (const float*)d_in[7];
    const float* wout   = (const float*)d_in[8];
    float* out = (float*)d_out;

    char* ws = (char*)d_ws;
    int*    table_base = (int*)(ws);                              // 4.03 MB
    int*    table   = table_base + GUARD;
    int*    packed  = (int*)(ws + (4352u<<10));                   // 128 KB
    int*    keyb    = (int*)(ws + (4608u<<10));                   // 128 KB
    int*    nbr     = (int*)(ws + (4864u<<10));                   // 1 MB
    int*    flagcnt = (int*)(ws + (5888u<<10));                   // 4 B
    int*    flaglist= (int*)(ws + (5892u<<10));                   // 128 KB
    float*  part1   = (float*)(ws + (6144u<<10));                 // 2 MB (2048 x 256)
    float*  part2   = (float*)(ws + (8192u<<10));                 // 512 KB (512 x 256)
    float*  scale1  = (float*)(ws + (8704u<<10));
    float*  shift1  = scale1 + 128;
    float*  scale2  = shift1 + 128;
    float*  shift2  = scale2 + 128;
    ushort* w3f     = (ushort*)(ws + (8960u<<10));                // 0.88 MB
    ushort* hb      = (ushort*)(ws + (10240u<<10));               // 8 MB
    float*  h       = (float*)(ws + (18432u<<10));                // 16 MB
    float*  h2      = h;   // alias: h dead once hb written; conv3 reads only hb

    hipMemsetAsync(table_base, 0xFF, (TBL + GUARD) * sizeof(int), stream);
    hipMemsetAsync(flagcnt, 0, sizeof(int), stream);
    prep_kernel       <<<N_/256, 256, 0, stream>>>(coords, table, packed, keyb);
    w3pack_kernel     <<<216, 256, 0, stream>>>(w3, w3f);
    knn_window_kernel <<<N_/64, 256, 0, stream>>>(table, keyb, nbr, flagcnt, flaglist);
    knn_bf_kernel     <<<256, 256, 0, stream>>>(packed, flagcnt, flaglist, nbr);
    h1_kernel         <<<N_/16, 256, 0, stream>>>(feats, nbr, w1, h, part1);
    stats_kernel      <<<1, 128, 0, stream>>>(part1, 2048, g1, b1, scale1, shift1);
    bnrelu_bf16_kernel<<<(N_*128/4)/256, 256, 0, stream>>>(h, scale1, shift1, hb);
    conv3_mfma_kernel <<<N_/128, 256, 0, stream>>>(hb, w3f, table, keyb, h2, part2);
    stats_kernel      <<<1, 128, 0, stream>>>(part2, 512, g2, b2, scale2, shift2);
    out_kernel        <<<N_/16, 256, 0, stream>>>(h2, wout, scale2, shift2, out);
}

// Round 5
// 331.855 us; speedup vs baseline: 2.7418x; 2.7418x over previous
//
#include <hip/hip_runtime.h>
#include <hip/hip_bf16.h>

#define B_   4
#define M_   8192
#define N_   32768
#define EPS_ 1e-5f
#define TBL  1048576   // 4 * 64^3 dense hash table
#define GUARD 8192     // negative-offset guard for window probes

typedef short short8 __attribute__((ext_vector_type(8)));   // 8 bf16 (4 VGPRs)
typedef float f32x4  __attribute__((ext_vector_type(4)));   // 4 fp32 acc

// ---------------------------------------------------------------- prep
__global__ __launch_bounds__(256) void prep_kernel(const int* __restrict__ coords,
                                                   int* __restrict__ table,
                                                   int* __restrict__ packed,
                                                   int* __restrict__ keyb) {
    int n = blockIdx.x * 256 + threadIdx.x;
    int b = coords[4*n+0], x = coords[4*n+1], y = coords[4*n+2], z = coords[4*n+3];
    packed[n] = (x << 10) | (y << 5) | z;
    int key = ((b*64 + x+1)*64 + y+1)*64 + (z+1);
    keyb[n] = key;
    table[key] = n;
}

// ---------------------------------------------------------------- w3 -> bf16 MFMA B-fragment layout
__global__ __launch_bounds__(256) void w3pack_kernel(const float* __restrict__ w3,
                                                     ushort* __restrict__ w3f) {
    int t = blockIdx.x * 256 + threadIdx.x;   // 27*2048 = 55296 threads exactly
    int lane = t & 63;
    int ct   = (t >> 6) & 7;
    int ks   = (t >> 9) & 3;
    int o    = t >> 11;
    int quad = lane >> 4, l15 = lane & 15;
    int n = ct*16 + l15;
    const float* src = w3 + o*16384;
    ushort out8[8];
#pragma unroll
    for (int j = 0; j < 8; ++j) {
        int c = ks*32 + quad*8 + j;
        float v = src[c*128 + n];
        __hip_bfloat16 bv = __float2bfloat16(v);
        ushort u; __builtin_memcpy(&u, &bv, 2);
        out8[j] = u;
    }
    *(uint4*)&w3f[t*8] = *(uint4*)out8;
}

// ---------------------------------------------------------------- kNN via radius-2 window
__global__ __launch_bounds__(256) void knn_window_kernel(const int* __restrict__ table,
                                                         const int* __restrict__ keyb,
                                                         int* __restrict__ nbr,
                                                         int* __restrict__ flagcnt,
                                                         int* __restrict__ flaglist) {
    __shared__ int okey_sh[125], d2_sh[125];
    __shared__ int tops[256 * 8];
    int tid = threadIdx.x;
    if (tid < 125) {
        int dx = tid / 25 - 2, rr = tid % 25, dy = rr / 5 - 2, dz = rr % 5 - 2;
        okey_sh[tid] = dx * 4096 + dy * 64 + dz;
        d2_sh[tid]   = dx*dx + dy*dy + dz*dz;
    }
    __syncthreads();

    int q   = blockIdx.x * 64 + (tid >> 2);
    int sub = tid & 3;
    int kb  = keyb[q];

    int top[8];
#pragma unroll
    for (int k = 0; k < 8; ++k) top[k] = 0x7FFFFFFF;

    int base = sub * 32;
    int cnt  = (sub == 3) ? 29 : 32;
    for (int i = 0; i < cnt; ++i) {
        int idx = base + i;
        int j = table[kb + okey_sh[idx]];
        if (j >= 0) {
            int key = (d2_sh[idx] << 13) | (j & 8191);
            if (key < top[7]) {
#pragma unroll
                for (int k = 7; k >= 1; --k)
                    top[k] = (key < top[k]) ? max(key, top[k-1]) : top[k];
                top[0] = min(key, top[0]);
            }
        }
    }
#pragma unroll
    for (int k = 0; k < 8; ++k) tops[tid*8 + k] = top[k];
    __syncthreads();

    if (sub == 0) {
        const int* L = &tops[tid*8];
        int ia0 = 0, ia1 = 0, ia2 = 0, ia3 = 0;
        int res[8];
#pragma unroll
        for (int k = 0; k < 8; ++k) {
            int v0 = L[ia0], v1 = L[8 + ia1], v2 = L[16 + ia2], v3 = L[24 + ia3];
            int m01 = min(v0, v1), m23 = min(v2, v3);
            int m = min(m01, m23);
            res[k] = m;
            if (m == v0) ++ia0; else if (m == v1) ++ia1;
            else if (m == v2) ++ia2; else ++ia3;
        }
        int bb = q & ~(M_-1);
        if ((res[7] >> 13) <= 8) {
#pragma unroll
            for (int k = 0; k < 8; ++k) nbr[q*8 + k] = bb + (res[k] & 8191);
        } else {
            int pos = atomicAdd(flagcnt, 1);
            flaglist[pos] = q;
        }
    }
}

// ---------------------------------------------------------------- brute-force cleanup
__global__ __launch_bounds__(256) void knn_bf_kernel(const int* __restrict__ packed,
                                                     const int* __restrict__ flagcnt,
                                                     const int* __restrict__ flaglist,
                                                     int* __restrict__ nbr) {
    __shared__ int tops[256 * 8];
    int tid = threadIdx.x;
    int cnt = *flagcnt;
    for (int f = blockIdx.x; f < cnt; f += gridDim.x) {
        int n = flaglist[f];
        int bb = n & ~(M_-1);
        int p = packed[n];
        int qx = (p >> 10) & 31, qy = (p >> 5) & 31, qz = p & 31;
        int top[8];
#pragma unroll
        for (int k = 0; k < 8; ++k) top[k] = 0x7FFFFFFF;
        for (int j = tid; j < M_; j += 256) {
            int c = packed[bb + j];
            int dx = qx - ((c >> 10) & 31);
            int dy = qy - ((c >> 5) & 31);
            int dz = qz - (c & 31);
            int d2 = dx*dx + dy*dy + dz*dz;
            int key = (d2 << 13) | j;
            if (key < top[7]) {
#pragma unroll
                for (int k = 7; k >= 1; --k)
                    top[k] = (key < top[k]) ? max(key, top[k-1]) : top[k];
                top[0] = min(key, top[0]);
            }
        }
#pragma unroll
        for (int k = 0; k < 8; ++k) tops[tid*8 + k] = top[k];
        __syncthreads();
        for (int stride = 128; stride >= 1; stride >>= 1) {
            if (tid < stride) {
                int* A  = &tops[tid*8];
                int* Bp = &tops[(tid+stride)*8];
                int r[8]; int ia = 0, ib = 0;
#pragma unroll
                for (int k = 0; k < 8; ++k) {
                    int a = A[ia], b2 = Bp[ib];
                    if (a <= b2) { r[k] = a; ++ia; } else { r[k] = b2; ++ib; }
                }
#pragma unroll
                for (int k = 0; k < 8; ++k) A[k] = r[k];
            }
            __syncthreads();
        }
        if (tid == 0) {
#pragma unroll
            for (int k = 0; k < 8; ++k) nbr[n*8 + k] = bb + (tops[k] & 8191);
        }
        __syncthreads();
    }
}

// ---------------------------------------------------------------- 1x1 conv + BN1 partials
__global__ __launch_bounds__(256) void h1_kernel(const float* __restrict__ feats,
                                                 const int* __restrict__ nbr,
                                                 const float* __restrict__ w1,
                                                 float* __restrict__ hpre,
                                                 float* __restrict__ part1) {
    __shared__ float comb[16][72];
    __shared__ float red[256];
    int tid = threadIdx.x;
    int rowbase = blockIdx.x * 16;
    if (tid < 144) {
        int r = tid / 9, s = tid % 9;
        int grow = rowbase + r;
        int idx = (s == 0) ? grow : nbr[grow*8 + (s-1)];
        const float4* f = (const float4*)(feats + idx * 8);
        float4 a = f[0], b = f[1];
        float* dp = &comb[r][s*8];
        dp[0]=a.x; dp[1]=a.y; dp[2]=a.z; dp[3]=a.w;
        dp[4]=b.x; dp[5]=b.y; dp[6]=b.z; dp[7]=b.w;
    }
    __syncthreads();
    int c = tid & 127, rh = tid >> 7;
    float acc[8];
#pragma unroll
    for (int i = 0; i < 8; ++i) acc[i] = 0.f;
    for (int s = 0; s < 72; ++s) {
        float w = w1[s*128 + c];
#pragma unroll
        for (int i = 0; i < 8; ++i)
            acc[i] += comb[rh*8 + i][s] * w;
    }
    float s1 = 0.f, q1 = 0.f;
#pragma unroll
    for (int i = 0; i < 8; ++i) {
        hpre[(rowbase + rh*8 + i)*128 + c] = acc[i];
        s1 += acc[i]; q1 += acc[i]*acc[i];
    }
    red[tid] = s1;
    __syncthreads();
    if (tid < 128) part1[blockIdx.x*256 + tid] = red[tid] + red[tid+128];
    __syncthreads();
    red[tid] = q1;
    __syncthreads();
    if (tid < 128) part1[blockIdx.x*256 + 128 + tid] = red[tid] + red[tid+128];
}

// ---------------------------------------------------------------- second-level partial reduce
// grid 16 x 256 threads: dst[b*256+t] = sum_{i<nsrc} src[(b*nsrc+i)*256 + t]
__global__ __launch_bounds__(256) void part_reduce_kernel(const float* __restrict__ src,
                                                          int nsrc,
                                                          float* __restrict__ dst) {
    int tid = threadIdx.x;
    const float* p = src + (size_t)blockIdx.x * nsrc * 256 + tid;
    float s = 0.f;
    for (int i = 0; i < nsrc; ++i) s += p[(size_t)i * 256];
    dst[blockIdx.x * 256 + tid] = s;
}

// ---------------------------------------------------------------- BN stats (over nb partial blocks)
__global__ __launch_bounds__(128) void stats_kernel(const float* __restrict__ part, int nb,
                                                    const float* __restrict__ g,
                                                    const float* __restrict__ bias,
                                                    float* __restrict__ scale,
                                                    float* __restrict__ shift) {
    int c = threadIdx.x;
    float s = 0.f, q = 0.f;
    for (int b = 0; b < nb; ++b) {
        s += part[b*256 + c];
        q += part[b*256 + 128 + c];
    }
    float mu  = s / (float)N_;
    float var = q / (float)N_ - mu*mu;
    float inv = rsqrtf(var + EPS_);
    float sc  = inv * g[c];
    scale[c] = sc;
    shift[c] = bias[c] - mu * sc;
}

// BN+ReLU -> bf16 (conv3 A operand)
__global__ __launch_bounds__(256) void bnrelu_bf16_kernel(const float* __restrict__ x,
                                                          const float* __restrict__ scale,
                                                          const float* __restrict__ shift,
                                                          ushort* __restrict__ y) {
    int i = blockIdx.x * 256 + threadIdx.x;
    float4 v = ((const float4*)x)[i];
    int c = (i * 4) & 127;
    v.x = fmaxf(0.f, v.x*scale[c]   + shift[c]);
    v.y = fmaxf(0.f, v.y*scale[c+1] + shift[c+1]);
    v.z = fmaxf(0.f, v.z*scale[c+2] + shift[c+2]);
    v.w = fmaxf(0.f, v.w*scale[c+3] + shift[c+3]);
    ushort o[4];
#pragma unroll
    for (int k = 0; k < 4; ++k) {
        float f = (&v.x)[k];
        __hip_bfloat16 bv = __float2bfloat16(f);
        __builtin_memcpy(&o[k], &bv, 2);
    }
    ((ushort4*)y)[i] = make_ushort4(o[0], o[1], o[2], o[3]);
}

// ---------------------------------------------------------------- 3^3 sparse conv: dbuf bf16 MFMA gather-GEMM
#define ASTR 136    // 128 + 8 ushorts pad: 2-way banks only (free), 16B aligned
__global__ __launch_bounds__(256, 1) void conv3_mfma_kernel(const ushort* __restrict__ hb,
                                                            const ushort* __restrict__ w3f,
                                                            const int* __restrict__ table,
                                                            const int* __restrict__ keyb,
                                                            float* __restrict__ h2,
                                                            float* __restrict__ part2) {
    __shared__ ushort As[2][128 * ASTR];   // 2 x 34816 B
    __shared__ ushort Bs[2][16384];        // 2 x 32768 B
    __shared__ int jsh[2][128];
    int tid = threadIdx.x;
    int lane = tid & 63, wid = tid >> 6;
    int quad = lane >> 4, l15 = lane & 15;
    int rg = wid >> 1, cg = wid & 1;       // row-group / col-group (64 each)
    int rowbase = blockIdx.x * 128;

    f32x4 acc[4][4];
#pragma unroll
    for (int rt = 0; rt < 4; ++rt)
#pragma unroll
        for (int ct = 0; ct < 4; ++ct)
            acc[rt][ct] = (f32x4){0.f, 0.f, 0.f, 0.f};

    const int gr = tid >> 4, gc16 = tid & 15;

#define OKEY(o) (((o)/9 - 1)*4096 + (((o)/3)%3 - 1)*64 + ((o)%3 - 1))

    if (tid < 128) jsh[0][tid] = table[keyb[rowbase + tid] + OKEY(0)];
    else           jsh[1][tid-128] = table[keyb[rowbase + tid-128] + OKEY(1)];
    __syncthreads();
    {
        uint4 a[8], b[8];
#pragma unroll
        for (int i = 0; i < 8; ++i) {
            int r = gr + 16*i;
            int j = jsh[0][r];
            a[i] = (j >= 0) ? *(const uint4*)&hb[j*128 + gc16*8] : make_uint4(0,0,0,0);
            b[i] = *(const uint4*)&w3f[(i*256 + tid)*8];
        }
#pragma unroll
        for (int i = 0; i < 8; ++i) {
            int r = gr + 16*i;
            *(uint4*)&As[0][r*ASTR + gc16*8] = a[i];
            *(uint4*)&Bs[0][(i*256 + tid)*8] = b[i];
        }
    }
    __syncthreads();

    for (int o = 0; o < 27; ++o) {
        int p = o & 1;
        uint4 pa[8], pb[8];
        int pj = 0;
        bool pre  = (o + 1 < 27);
        bool pre2 = (o + 2 < 27);
        if (pre) {
            const ushort* wsrc = w3f + (o+1)*16384;
#pragma unroll
            for (int i = 0; i < 8; ++i) {
                int r = gr + 16*i;
                int j = jsh[p^1][r];
                pa[i] = (j >= 0) ? *(const uint4*)&hb[j*128 + gc16*8] : make_uint4(0,0,0,0);
                pb[i] = *(const uint4*)&wsrc[(i*256 + tid)*8];
            }
        }
        if (pre2 && tid < 128) pj = table[keyb[rowbase + tid] + OKEY(o+2)];

#pragma unroll
        for (int ks = 0; ks < 4; ++ks) {
            short8 af[4], bfr[4];
#pragma unroll
            for (int rt = 0; rt < 4; ++rt)
                af[rt] = *(const short8*)&As[p][(rg*64 + rt*16 + l15)*ASTR + ks*32 + quad*8];
#pragma unroll
            for (int ct = 0; ct < 4; ++ct)
                bfr[ct] = *(const short8*)&Bs[p][((ks*8 + cg*4 + ct)*64 + lane)*8];
#pragma unroll
            for (int rt = 0; rt < 4; ++rt)
#pragma unroll
                for (int ct = 0; ct < 4; ++ct)
                    acc[rt][ct] = __builtin_amdgcn_mfma_f32_16x16x32_bf16(af[rt], bfr[ct], acc[rt][ct], 0, 0, 0);
        }

        if (pre) {
#pragma unroll
            for (int i = 0; i < 8; ++i) {
                int r = gr + 16*i;
                *(uint4*)&As[p^1][r*ASTR + gc16*8] = pa[i];
                *(uint4*)&Bs[p^1][(i*256 + tid)*8] = pb[i];
            }
        }
        if (pre2 && tid < 128) jsh[p][tid] = pj;
        __syncthreads();
    }

    // epilogue: store h2 + BN2 partials (sum/sumsq per column)
    float s[4] = {0,0,0,0}, q[4] = {0,0,0,0};
#pragma unroll
    for (int rt = 0; rt < 4; ++rt)
#pragma unroll
        for (int ct = 0; ct < 4; ++ct)
#pragma unroll
            for (int r = 0; r < 4; ++r) {
                float v = acc[rt][ct][r];
                int row = rowbase + rg*64 + rt*16 + quad*4 + r;
                int col = cg*64 + ct*16 + l15;
                h2[row*128 + col] = v;
                s[ct] += v; q[ct] += v*v;
            }
#pragma unroll
    for (int ct = 0; ct < 4; ++ct) {
        s[ct] += __shfl_xor(s[ct], 16); s[ct] += __shfl_xor(s[ct], 32);
        q[ct] += __shfl_xor(q[ct], 16); q[ct] += __shfl_xor(q[ct], 32);
    }
    if (quad == 0) {
        int base = (blockIdx.x*2 + rg)*256;
#pragma unroll
        for (int ct = 0; ct < 4; ++ct) {
            part2[base + cg*64 + ct*16 + l15]       = s[ct];
            part2[base + 128 + cg*64 + ct*16 + l15] = q[ct];
        }
    }
}

// ---------------------------------------------------------------- fused BN2+ReLU+final 1x1 conv
__global__ __launch_bounds__(256) void out_kernel(const float* __restrict__ h2,
                                                  const float* __restrict__ wout,
                                                  const float* __restrict__ scale,
                                                  const float* __restrict__ shift,
                                                  float* __restrict__ out) {
    int tid = threadIdx.x;
    int r = tid >> 4, d = tid & 15;
    int row = blockIdx.x * 16 + r;
    float acc = 0.f;
    for (int c = 0; c < 128; ++c) {
        float v = fmaxf(0.f, h2[row*128 + c]*scale[c] + shift[c]);
        acc += v * wout[c*16 + d];
    }
    out[row*16 + d] = acc;
}

// ---------------------------------------------------------------- launch
extern "C" void kernel_launch(void* const* d_in, const int* in_sizes, int n_in,
                              void* d_out, int out_size, void* d_ws, size_t ws_size,
                              hipStream_t stream) {
    const int*   coords = (const int*)d_in[0];
    const float* feats  = (const float*)d_in[1];
    const float* w1     = (const float*)d_in[2];
    const float* g1     = (const float*)d_in[3];
    const float* b1     = (const float*)d_in[4];
    const float* w3     = (const float*)d_in[5];
    const float* g2     = (const float*)d_in[6];
    const float* b2     = (const float*)d_in[7];
    const float* wout   = (const float*)d_in[8];
    float* out = (float*)d_out;

    char* ws = (char*)d_ws;
    int*    table_base = (int*)(ws);                              // 4.03 MB
    int*    table   = table_base + GUARD;
    int*    packed  = (int*)(ws + (4352u<<10));                   // 128 KB
    int*    keyb    = (int*)(ws + (4608u<<10));                   // 128 KB
    int*    nbr     = (int*)(ws + (4864u<<10));                   // 1 MB
    int*    flagcnt = (int*)(ws + (5888u<<10));                   // 4 B
    int*    flaglist= (int*)(ws + (5892u<<10));                   // 128 KB
    float*  part1   = (float*)(ws + (6144u<<10));                 // 2 MB (2048 x 256)
    float*  part2   = (float*)(ws + (8192u<<10));                 // 512 KB (512 x 256)
    float*  scale1  = (float*)(ws + (8704u<<10));
    float*  shift1  = scale1 + 128;
    float*  scale2  = shift1 + 128;
    float*  shift2  = scale2 + 128;
    ushort* w3f     = (ushort*)(ws + (8960u<<10));                // 0.88 MB
    float*  dst1    = (float*)(ws + (9984u<<10));                 // 16 KB (16 x 256)
    float*  dst2    = dst1 + 16*256;                              // 16 KB
    ushort* hb      = (ushort*)(ws + (10240u<<10));               // 8 MB
    float*  h       = (float*)(ws + (18432u<<10));                // 16 MB
    float*  h2      = h;   // alias: h dead once hb written; conv3 reads only hb

    hipMemsetAsync(table_base, 0xFF, (TBL + GUARD) * sizeof(int), stream);
    hipMemsetAsync(flagcnt, 0, sizeof(int), stream);
    prep_kernel       <<<N_/256, 256, 0, stream>>>(coords, table, packed, keyb);
    w3pack_kernel     <<<216, 256, 0, stream>>>(w3, w3f);
    knn_window_kernel <<<N_/64, 256, 0, stream>>>(table, keyb, nbr, flagcnt, flaglist);
    knn_bf_kernel     <<<256, 256, 0, stream>>>(packed, flagcnt, flaglist, nbr);
    h1_kernel         <<<N_/16, 256, 0, stream>>>(feats, nbr, w1, h, part1);
    part_reduce_kernel<<<16, 256, 0, stream>>>(part1, 128, dst1);
    stats_kernel      <<<1, 128, 0, stream>>>(dst1, 16, g1, b1, scale1, shift1);
    bnrelu_bf16_kernel<<<(N_*128/4)/256, 256, 0, stream>>>(h, scale1, shift1, hb);
    conv3_mfma_kernel <<<N_/128, 256, 0, stream>>>(hb, w3f, table, keyb, h2, part2);
    part_reduce_kernel<<<16, 256, 0, stream>>>(part2, 32, dst2);
    stats_kernel      <<<1, 128, 0, stream>>>(dst2, 16, g2, b2, scale2, shift2);
    out_kernel        <<<N_/16, 256, 0, stream>>>(h2, wout, scale2, shift2, out);
}

// Round 6
// 280.532 us; speedup vs baseline: 3.2434x; 1.1829x over previous
//
#include <hip/hip_runtime.h>
#include <hip/hip_bf16.h>

#define B_   4
#define M_   8192
#define N_   32768
#define EPS_ 1e-5f
#define TBL  1048576   // 4 * 64^3 dense hash table
#define GUARD 8192     // negative-offset guard for window probes

typedef short short8 __attribute__((ext_vector_type(8)));   // 8 bf16 (4 VGPRs)
typedef float f32x4  __attribute__((ext_vector_type(4)));   // 4 fp32 acc

// ---------------------------------------------------------------- prep
__global__ __launch_bounds__(256) void prep_kernel(const int* __restrict__ coords,
                                                   int* __restrict__ table,
                                                   int* __restrict__ packed,
                                                   int* __restrict__ keyb) {
    int n = blockIdx.x * 256 + threadIdx.x;
    int b = coords[4*n+0], x = coords[4*n+1], y = coords[4*n+2], z = coords[4*n+3];
    packed[n] = (x << 10) | (y << 5) | z;
    int key = ((b*64 + x+1)*64 + y+1)*64 + (z+1);
    keyb[n] = key;
    table[key] = n;
}

// ---------------------------------------------------------------- w3 -> bf16 MFMA B-fragment layout
// w3f[t*8+j], t = (o<<11)|(ks<<9)|(ct<<6)|lane :
//   value = bf16(w3[o][c][n]), c = ks*32 + (lane>>4)*8 + j, n = ct*16 + (lane&15)
__global__ __launch_bounds__(256) void w3pack_kernel(const float* __restrict__ w3,
                                                     ushort* __restrict__ w3f) {
    int t = blockIdx.x * 256 + threadIdx.x;   // 27*2048 = 55296 threads exactly
    int lane = t & 63;
    int ct   = (t >> 6) & 7;
    int ks   = (t >> 9) & 3;
    int o    = t >> 11;
    int quad = lane >> 4, l15 = lane & 15;
    int n = ct*16 + l15;
    const float* src = w3 + o*16384;
    ushort out8[8];
#pragma unroll
    for (int j = 0; j < 8; ++j) {
        int c = ks*32 + quad*8 + j;
        float v = src[c*128 + n];
        __hip_bfloat16 bv = __float2bfloat16(v);
        ushort u; __builtin_memcpy(&u, &bv, 2);
        out8[j] = u;
    }
    *(uint4*)&w3f[t*8] = *(uint4*)out8;
}

// ---------------------------------------------------------------- kNN via radius-2 window
__global__ __launch_bounds__(256) void knn_window_kernel(const int* __restrict__ table,
                                                         const int* __restrict__ keyb,
                                                         int* __restrict__ nbr,
                                                         int* __restrict__ flagcnt,
                                                         int* __restrict__ flaglist) {
    __shared__ int okey_sh[125], d2_sh[125];
    __shared__ int tops[256 * 8];
    int tid = threadIdx.x;
    if (tid < 125) {
        int dx = tid / 25 - 2, rr = tid % 25, dy = rr / 5 - 2, dz = rr % 5 - 2;
        okey_sh[tid] = dx * 4096 + dy * 64 + dz;
        d2_sh[tid]   = dx*dx + dy*dy + dz*dz;
    }
    __syncthreads();

    int q   = blockIdx.x * 64 + (tid >> 2);
    int sub = tid & 3;
    int kb  = keyb[q];

    int top[8];
#pragma unroll
    for (int k = 0; k < 8; ++k) top[k] = 0x7FFFFFFF;

    int base = sub * 32;
    int cnt  = (sub == 3) ? 29 : 32;
    for (int i = 0; i < cnt; ++i) {
        int idx = base + i;
        int j = table[kb + okey_sh[idx]];
        if (j >= 0) {
            int key = (d2_sh[idx] << 13) | (j & 8191);
            if (key < top[7]) {
#pragma unroll
                for (int k = 7; k >= 1; --k)
                    top[k] = (key < top[k]) ? max(key, top[k-1]) : top[k];
                top[0] = min(key, top[0]);
            }
        }
    }
#pragma unroll
    for (int k = 0; k < 8; ++k) tops[tid*8 + k] = top[k];
    __syncthreads();

    if (sub == 0) {
        const int* L = &tops[tid*8];
        int ia0 = 0, ia1 = 0, ia2 = 0, ia3 = 0;
        int res[8];
#pragma unroll
        for (int k = 0; k < 8; ++k) {
            int v0 = L[ia0], v1 = L[8 + ia1], v2 = L[16 + ia2], v3 = L[24 + ia3];
            int m01 = min(v0, v1), m23 = min(v2, v3);
            int m = min(m01, m23);
            res[k] = m;
            if (m == v0) ++ia0; else if (m == v1) ++ia1;
            else if (m == v2) ++ia2; else ++ia3;
        }
        int bb = q & ~(M_-1);
        if ((res[7] >> 13) <= 8) {
#pragma unroll
            for (int k = 0; k < 8; ++k) nbr[q*8 + k] = bb + (res[k] & 8191);
        } else {
            int pos = atomicAdd(flagcnt, 1);
            flaglist[pos] = q;
        }
    }
}

// ---------------------------------------------------------------- brute-force cleanup
__global__ __launch_bounds__(256) void knn_bf_kernel(const int* __restrict__ packed,
                                                     const int* __restrict__ flagcnt,
                                                     const int* __restrict__ flaglist,
                                                     int* __restrict__ nbr) {
    __shared__ int tops[256 * 8];
    int tid = threadIdx.x;
    int cnt = *flagcnt;
    for (int f = blockIdx.x; f < cnt; f += gridDim.x) {
        int n = flaglist[f];
        int bb = n & ~(M_-1);
        int p = packed[n];
        int qx = (p >> 10) & 31, qy = (p >> 5) & 31, qz = p & 31;
        int top[8];
#pragma unroll
        for (int k = 0; k < 8; ++k) top[k] = 0x7FFFFFFF;
        for (int j = tid; j < M_; j += 256) {
            int c = packed[bb + j];
            int dx = qx - ((c >> 10) & 31);
            int dy = qy - ((c >> 5) & 31);
            int dz = qz - (c & 31);
            int d2 = dx*dx + dy*dy + dz*dz;
            int key = (d2 << 13) | j;
            if (key < top[7]) {
#pragma unroll
                for (int k = 7; k >= 1; --k)
                    top[k] = (key < top[k]) ? max(key, top[k-1]) : top[k];
                top[0] = min(key, top[0]);
            }
        }
#pragma unroll
        for (int k = 0; k < 8; ++k) tops[tid*8 + k] = top[k];
        __syncthreads();
        for (int stride = 128; stride >= 1; stride >>= 1) {
            if (tid < stride) {
                int* A  = &tops[tid*8];
                int* Bp = &tops[(tid+stride)*8];
                int r[8]; int ia = 0, ib = 0;
#pragma unroll
                for (int k = 0; k < 8; ++k) {
                    int a = A[ia], b2 = Bp[ib];
                    if (a <= b2) { r[k] = a; ++ia; } else { r[k] = b2; ++ib; }
                }
#pragma unroll
                for (int k = 0; k < 8; ++k) A[k] = r[k];
            }
            __syncthreads();
        }
        if (tid == 0) {
#pragma unroll
            for (int k = 0; k < 8; ++k) nbr[n*8 + k] = bb + (tops[k] & 8191);
        }
        __syncthreads();
    }
}

// ---------------------------------------------------------------- 1x1 conv + BN1 partials
__global__ __launch_bounds__(256) void h1_kernel(const float* __restrict__ feats,
                                                 const int* __restrict__ nbr,
                                                 const float* __restrict__ w1,
                                                 float* __restrict__ hpre,
                                                 float* __restrict__ part1) {
    __shared__ float comb[16][72];
    __shared__ float red[256];
    int tid = threadIdx.x;
    int rowbase = blockIdx.x * 16;
    if (tid < 144) {
        int r = tid / 9, s = tid % 9;
        int grow = rowbase + r;
        int idx = (s == 0) ? grow : nbr[grow*8 + (s-1)];
        const float4* f = (const float4*)(feats + idx * 8);
        float4 a = f[0], b = f[1];
        float* dp = &comb[r][s*8];
        dp[0]=a.x; dp[1]=a.y; dp[2]=a.z; dp[3]=a.w;
        dp[4]=b.x; dp[5]=b.y; dp[6]=b.z; dp[7]=b.w;
    }
    __syncthreads();
    int c = tid & 127, rh = tid >> 7;
    float acc[8];
#pragma unroll
    for (int i = 0; i < 8; ++i) acc[i] = 0.f;
    for (int s = 0; s < 72; ++s) {
        float w = w1[s*128 + c];
#pragma unroll
        for (int i = 0; i < 8; ++i)
            acc[i] += comb[rh*8 + i][s] * w;
    }
    float s1 = 0.f, q1 = 0.f;
#pragma unroll
    for (int i = 0; i < 8; ++i) {
        hpre[(rowbase + rh*8 + i)*128 + c] = acc[i];
        s1 += acc[i]; q1 += acc[i]*acc[i];
    }
    red[tid] = s1;
    __syncthreads();
    if (tid < 128) part1[blockIdx.x*256 + tid] = red[tid] + red[tid+128];
    __syncthreads();
    red[tid] = q1;
    __syncthreads();
    if (tid < 128) part1[blockIdx.x*256 + 128 + tid] = red[tid] + red[tid+128];
}

// ---------------------------------------------------------------- second-level partial reduce
__global__ __launch_bounds__(256) void part_reduce_kernel(const float* __restrict__ src,
                                                          int nsrc,
                                                          float* __restrict__ dst) {
    int tid = threadIdx.x;
    const float* p = src + (size_t)blockIdx.x * nsrc * 256 + tid;
    float s = 0.f;
    for (int i = 0; i < nsrc; ++i) s += p[(size_t)i * 256];
    dst[blockIdx.x * 256 + tid] = s;
}

// ---------------------------------------------------------------- BN stats (over nb partial blocks)
__global__ __launch_bounds__(128) void stats_kernel(const float* __restrict__ part, int nb,
                                                    const float* __restrict__ g,
                                                    const float* __restrict__ bias,
                                                    float* __restrict__ scale,
                                                    float* __restrict__ shift) {
    int c = threadIdx.x;
    float s = 0.f, q = 0.f;
    for (int b = 0; b < nb; ++b) {
        s += part[b*256 + c];
        q += part[b*256 + 128 + c];
    }
    float mu  = s / (float)N_;
    float var = q / (float)N_ - mu*mu;
    float inv = rsqrtf(var + EPS_);
    float sc  = inv * g[c];
    scale[c] = sc;
    shift[c] = bias[c] - mu * sc;
}

// BN+ReLU -> bf16 (conv3 A operand)
__global__ __launch_bounds__(256) void bnrelu_bf16_kernel(const float* __restrict__ x,
                                                          const float* __restrict__ scale,
                                                          const float* __restrict__ shift,
                                                          ushort* __restrict__ y) {
    int i = blockIdx.x * 256 + threadIdx.x;
    float4 v = ((const float4*)x)[i];
    int c = (i * 4) & 127;
    v.x = fmaxf(0.f, v.x*scale[c]   + shift[c]);
    v.y = fmaxf(0.f, v.y*scale[c+1] + shift[c+1]);
    v.z = fmaxf(0.f, v.z*scale[c+2] + shift[c+2]);
    v.w = fmaxf(0.f, v.w*scale[c+3] + shift[c+3]);
    ushort o[4];
#pragma unroll
    for (int k = 0; k < 4; ++k) {
        float f = (&v.x)[k];
        __hip_bfloat16 bv = __float2bfloat16(f);
        __builtin_memcpy(&o[k], &bv, 2);
    }
    ((ushort4*)y)[i] = make_ushort4(o[0], o[1], o[2], o[3]);
}

// ---------------------------------------------------------------- 3^3 sparse conv: LDS-free bf16 MFMA gather-GEMM
// 128x128 per block, 4 waves as 2x2 (wave = 64 rows x 64 cols = 4x4 16x16 tiles).
// A and B fragments are 16 contiguous bytes/lane -> loaded DIRECTLY global->VGPR:
//   A: hb[j*128 + ks*32 + quad*8]  (gather via dense table, zero-fill invalid)
//   B: w3f[o*16384 + ((ks*8+cb)*64+lane)*8]  (fragment-major pack, coalesced)
// No LDS, no barriers: 12 waves/CU (VGPR-bound) overlap loads with MFMA freely.
__global__ __launch_bounds__(256, 3) void conv3_mfma_kernel(const ushort* __restrict__ hb,
                                                            const ushort* __restrict__ w3f,
                                                            const int* __restrict__ table,
                                                            const int* __restrict__ keyb,
                                                            float* __restrict__ h2,
                                                            float* __restrict__ part2) {
    int tid = threadIdx.x;
    int lane = tid & 63, wid = tid >> 6;
    int quad = lane >> 4, l15 = lane & 15;
    int rg = wid >> 1, cg = wid & 1;
    int rowbase = blockIdx.x * 128;

    // hash keys for this lane's 4 A-rows (row = rg*64 + rt*16 + l15)
    int kb[4];
#pragma unroll
    for (int rt = 0; rt < 4; ++rt)
        kb[rt] = keyb[rowbase + rg*64 + rt*16 + l15];

    f32x4 acc[4][4];
#pragma unroll
    for (int rt = 0; rt < 4; ++rt)
#pragma unroll
        for (int ct = 0; ct < 4; ++ct)
            acc[rt][ct] = (f32x4){0.f, 0.f, 0.f, 0.f};

    const short8 zero8 = {};

    for (int o = 0; o < 27; ++o) {
        int okey = (o/9 - 1)*4096 + ((o/3)%3 - 1)*64 + (o%3 - 1);
        int j[4];
#pragma unroll
        for (int rt = 0; rt < 4; ++rt)
            j[rt] = table[kb[rt] + okey];
        const ushort* wo = w3f + o*16384;
#pragma unroll
        for (int ks = 0; ks < 4; ++ks) {
            short8 af[4], bfr[4];
#pragma unroll
            for (int rt = 0; rt < 4; ++rt) {
                int jr = j[rt];
                short8 v = *(const short8*)&hb[(size_t)max(jr, 0)*128 + ks*32 + quad*8];
                af[rt] = (jr >= 0) ? v : zero8;
            }
#pragma unroll
            for (int ct = 0; ct < 4; ++ct)
                bfr[ct] = *(const short8*)&wo[((ks*8 + cg*4 + ct)*64 + lane)*8];
#pragma unroll
            for (int rt = 0; rt < 4; ++rt)
#pragma unroll
                for (int ct = 0; ct < 4; ++ct)
                    acc[rt][ct] = __builtin_amdgcn_mfma_f32_16x16x32_bf16(af[rt], bfr[ct], acc[rt][ct], 0, 0, 0);
        }
    }

    // epilogue: store h2 + BN2 partials (sum/sumsq per column)
    float s[4] = {0,0,0,0}, q[4] = {0,0,0,0};
#pragma unroll
    for (int rt = 0; rt < 4; ++rt)
#pragma unroll
        for (int ct = 0; ct < 4; ++ct)
#pragma unroll
            for (int r = 0; r < 4; ++r) {
                float v = acc[rt][ct][r];
                int row = rowbase + rg*64 + rt*16 + quad*4 + r;
                int col = cg*64 + ct*16 + l15;
                h2[row*128 + col] = v;
                s[ct] += v; q[ct] += v*v;
            }
#pragma unroll
    for (int ct = 0; ct < 4; ++ct) {
        s[ct] += __shfl_xor(s[ct], 16); s[ct] += __shfl_xor(s[ct], 32);
        q[ct] += __shfl_xor(q[ct], 16); q[ct] += __shfl_xor(q[ct], 32);
    }
    if (quad == 0) {
        int base = (blockIdx.x*2 + rg)*256;
#pragma unroll
        for (int ct = 0; ct < 4; ++ct) {
            part2[base + cg*64 + ct*16 + l15]       = s[ct];
            part2[base + 128 + cg*64 + ct*16 + l15] = q[ct];
        }
    }
}

// ---------------------------------------------------------------- fused BN2+ReLU+final 1x1 conv
__global__ __launch_bounds__(256) void out_kernel(const float* __restrict__ h2,
                                                  const float* __restrict__ wout,
                                                  const float* __restrict__ scale,
                                                  const float* __restrict__ shift,
                                                  float* __restrict__ out) {
    int tid = threadIdx.x;
    int r = tid >> 4, d = tid & 15;
    int row = blockIdx.x * 16 + r;
    float acc = 0.f;
    for (int c = 0; c < 128; ++c) {
        float v = fmaxf(0.f, h2[row*128 + c]*scale[c] + shift[c]);
        acc += v * wout[c*16 + d];
    }
    out[row*16 + d] = acc;
}

// ---------------------------------------------------------------- launch
extern "C" void kernel_launch(void* const* d_in, const int* in_sizes, int n_in,
                              void* d_out, int out_size, void* d_ws, size_t ws_size,
                              hipStream_t stream) {
    const int*   coords = (const int*)d_in[0];
    const float* feats  = (const float*)d_in[1];
    const float* w1     = (const float*)d_in[2];
    const float* g1     = (const float*)d_in[3];
    const float* b1     = (const float*)d_in[4];
    const float* w3     = (const float*)d_in[5];
    const float* g2     = (const float*)d_in[6];
    const float* b2     = (const float*)d_in[7];
    const float* wout   = (const float*)d_in[8];
    float* out = (float*)d_out;

    char* ws = (char*)d_ws;
    int*    table_base = (int*)(ws);                              // 4.03 MB
    int*    table   = table_base + GUARD;
    int*    packed  = (int*)(ws + (4352u<<10));                   // 128 KB
    int*    keyb    = (int*)(ws + (4608u<<10));                   // 128 KB
    int*    nbr     = (int*)(ws + (4864u<<10));                   // 1 MB
    int*    flagcnt = (int*)(ws + (5888u<<10));                   // 4 B
    int*    flaglist= (int*)(ws + (5892u<<10));                   // 128 KB
    float*  part1   = (float*)(ws + (6144u<<10));                 // 2 MB (2048 x 256)
    float*  part2   = (float*)(ws + (8192u<<10));                 // 512 KB (512 x 256)
    float*  scale1  = (float*)(ws + (8704u<<10));
    float*  shift1  = scale1 + 128;
    float*  scale2  = shift1 + 128;
    float*  shift2  = scale2 + 128;
    ushort* w3f     = (ushort*)(ws + (8960u<<10));                // 0.88 MB
    float*  dst1    = (float*)(ws + (9984u<<10));                 // 16 KB (16 x 256)
    float*  dst2    = dst1 + 16*256;                              // 16 KB
    ushort* hb      = (ushort*)(ws + (10240u<<10));               // 8 MB
    float*  h       = (float*)(ws + (18432u<<10));                // 16 MB
    float*  h2      = h;   // alias: h dead once hb written; conv3 reads only hb

    hipMemsetAsync(table_base, 0xFF, (TBL + GUARD) * sizeof(int), stream);
    hipMemsetAsync(flagcnt, 0, sizeof(int), stream);
    prep_kernel       <<<N_/256, 256, 0, stream>>>(coords, table, packed, keyb);
    w3pack_kernel     <<<216, 256, 0, stream>>>(w3, w3f);
    knn_window_kernel <<<N_/64, 256, 0, stream>>>(table, keyb, nbr, flagcnt, flaglist);
    knn_bf_kernel     <<<256, 256, 0, stream>>>(packed, flagcnt, flaglist, nbr);
    h1_kernel         <<<N_/16, 256, 0, stream>>>(feats, nbr, w1, h, part1);
    part_reduce_kernel<<<16, 256, 0, stream>>>(part1, 128, dst1);
    stats_kernel      <<<1, 128, 0, stream>>>(dst1, 16, g1, b1, scale1, shift1);
    bnrelu_bf16_kernel<<<(N_*128/4)/256, 256, 0, stream>>>(h, scale1, shift1, hb);
    conv3_mfma_kernel <<<N_/128, 256, 0, stream>>>(hb, w3f, table, keyb, h2, part2);
    part_reduce_kernel<<<16, 256, 0, stream>>>(part2, 32, dst2);
    stats_kernel      <<<1, 128, 0, stream>>>(dst2, 16, g2, b2, scale2, shift2);
    out_kernel        <<<N_/16, 256, 0, stream>>>(h2, wout, scale2, shift2, out);
}